// Round 4
// baseline (633.650 us; speedup 1.0000x reference)
//
#include <hip/hip_runtime.h>
#include <hip/hip_bf16.h>
#include <math.h>

#define B_ 2
#define L_ 2048
#define DM_ 1024
#define DC_ 512
#define NH_ 8
#define DH_ 64
#define MR_ (B_*L_)   // 4096 rows
#define BH_ (B_*NH_)  // 16

typedef unsigned short u16;
typedef unsigned int u32;

static __device__ __forceinline__ u16 f2bf(float x) {
  union { float f; u32 u; } v; v.f = x;
  u32 r = (v.u + 0x7fffu + ((v.u >> 16) & 1u)) >> 16;  // RNE
  return (u16)r;
}
static __device__ __forceinline__ float bf2f(u16 x) {
  union { u32 u; float f; } v; v.u = ((u32)x) << 16;
  return v.f;
}

// ---------------------------------------------------------------------------
// Generic C = A @ W^T + bias GEMM. 64x64 tile, BK=16, 256 thr, 4x4/thread.
// MODE 0: Cf[m*Ndim+n] fp32
// MODE 2: Cf[m*Ndim+n] fp32, A split at k=512: k<512 from A (lda), else A2 (ld 512)
// MODE 3: bf16 heads layout Cb[((b*8+h)*L+l)*64+d]
// ---------------------------------------------------------------------------
template<int MODE>
__global__ __launch_bounds__(256) void gemm_k(
    const float* __restrict__ A, int lda,
    const float* __restrict__ A2,
    const float* __restrict__ W, int ldw,
    const float* __restrict__ bias,
    float* __restrict__ Cf, u16* __restrict__ Cb,
    int Ndim, int Kdim)
{
  __shared__ float As[16][68];
  __shared__ float Ws[16][68];
  const int tid = threadIdx.x;
  const int tx = tid & 15, ty = tid >> 4;
  const int m0 = blockIdx.y << 6, n0 = blockIdx.x << 6;
  const int lr = tid >> 2;          // 0..63
  const int lk = (tid & 3) << 2;    // 0,4,8,12
  float acc[4][4] = {};
  const float* Wp = W + (size_t)(n0 + lr) * ldw + lk;
  for (int k0 = 0; k0 < Kdim; k0 += 16) {
    const float* ap;
    if (MODE == 2 && k0 >= 512)
      ap = A2 + (size_t)(m0 + lr) * 512 + (k0 - 512) + lk;
    else
      ap = A + (size_t)(m0 + lr) * lda + k0 + lk;
    float4 a4 = *(const float4*)ap;
    float4 w4 = *(const float4*)(Wp + k0);
    As[lk+0][lr]=a4.x; As[lk+1][lr]=a4.y; As[lk+2][lr]=a4.z; As[lk+3][lr]=a4.w;
    Ws[lk+0][lr]=w4.x; Ws[lk+1][lr]=w4.y; Ws[lk+2][lr]=w4.z; Ws[lk+3][lr]=w4.w;
    __syncthreads();
#pragma unroll
    for (int kk = 0; kk < 16; ++kk) {
      float4 av = *(const float4*)&As[kk][ty<<2];
      float4 wv = *(const float4*)&Ws[kk][tx<<2];
      float a[4] = {av.x, av.y, av.z, av.w};
      float w[4] = {wv.x, wv.y, wv.z, wv.w};
#pragma unroll
      for (int i = 0; i < 4; ++i)
#pragma unroll
        for (int j = 0; j < 4; ++j)
          acc[i][j] = fmaf(a[i], w[j], acc[i][j]);
    }
    __syncthreads();
  }
#pragma unroll
  for (int i = 0; i < 4; ++i) {
    const int m = m0 + (ty<<2) + i;
    const int n = n0 + (tx<<2);
    float v0 = acc[i][0] + bias[n+0];
    float v1 = acc[i][1] + bias[n+1];
    float v2 = acc[i][2] + bias[n+2];
    float v3 = acc[i][3] + bias[n+3];
    if (MODE == 0 || MODE == 2) {
      *(float4*)(Cf + (size_t)m * Ndim + n) = make_float4(v0, v1, v2, v3);
    } else {
      const int b = m >> 11, l = m & (L_-1), h = n >> 6, d = n & (DH_-1);
      ushort4 o; o.x = f2bf(v0); o.y = f2bf(v1); o.z = f2bf(v2); o.w = f2bf(v3);
      *(ushort4*)(Cb + ((size_t)(b*NH_ + h) * L_ + l) * DH_ + d) = o;
    }
  }
}

// ---------------------------------------------------------------------------
// Saliency conv1d: sal[b][h][l] = sum_c sum_t x1[b][l+t-1][c]*cw[h][c][t] + cb[h]
// ---------------------------------------------------------------------------
__global__ __launch_bounds__(256) void conv_k(
    const float* __restrict__ src, const float* __restrict__ cw,
    const float* __restrict__ cb, float* __restrict__ sal)
{
  __shared__ float xs[34][260];
  const int b = blockIdx.y;
  const int l0 = blockIdx.x << 5;
  const int tid = threadIdx.x;
  const int li = tid >> 3, h = tid & 7;
  float acc = cb[h];
  for (int c0 = 0; c0 < DC_; c0 += 256) {
    __syncthreads();
    for (int t = tid; t < 34*64; t += 256) {
      const int r = t >> 6;
      const int c4 = (t & 63) << 2;
      const int l = l0 - 1 + r;
      float4 v = make_float4(0.f, 0.f, 0.f, 0.f);
      if (l >= 0 && l < L_)
        v = *(const float4*)(src + (size_t)(b*L_ + l) * DM_ + c0 + c4);
      *(float4*)&xs[r][c4] = v;
    }
    __syncthreads();
    for (int c = 0; c < 256; ++c) {
      const float* w = cw + ((size_t)h * DC_ + c0 + c) * 3;
      acc += xs[li+0][c]*w[0] + xs[li+1][c]*w[1] + xs[li+2][c]*w[2];
    }
  }
  sal[(size_t)(b*NH_ + h) * L_ + l0 + li] = acc;
}

// ---------------------------------------------------------------------------
// Attention: per (b,h, 64-q tile): scores=QK^T/8+sal[m], p=exp(scores) (no max
// subtraction: |scores| <~ 6), write unnormalized p (fp32), accumulate rowsum
// and ctx = P@K; normalize ctx in-kernel, emit invS for the attn rescale pass.
// Q/K inputs are bf16 heads-layout. LDS fp32: Qs[d][q], B1 = K[d][m] then
// Ps[q][m] (stride 69), Ksm[m][d].
// ---------------------------------------------------------------------------
__global__ __launch_bounds__(256) void attn_k(
    const u16* __restrict__ Qh, const u16* __restrict__ Kh,
    const float* __restrict__ sal, float* __restrict__ attn,
    float* __restrict__ invS, float* __restrict__ ctx)
{
  __shared__ float Qs[64*68];
  __shared__ float B1[64*69];
  __shared__ float Ksm[64*68];
  __shared__ float sal_s[64];
  __shared__ float inv_s[64];
  const int tid = threadIdx.x;
  const int tx = tid & 15, ty = tid >> 4;
  const int bh = blockIdx.y;
  const int q0 = blockIdx.x << 6;
  const u16* Qp = Qh + ((size_t)bh * L_ + q0) * DH_;
  const u16* Kp = Kh + (size_t)bh * L_ * DH_;
  {
    const int r = tid >> 4, d4 = (tid & 15) << 2;
#pragma unroll
    for (int p = 0; p < 4; ++p) {
      const int q = (p<<4) + r;
      ushort4 v = *(const ushort4*)(Qp + (size_t)q * DH_ + d4);
      Qs[(d4+0)*68+q]=bf2f(v.x); Qs[(d4+1)*68+q]=bf2f(v.y);
      Qs[(d4+2)*68+q]=bf2f(v.z); Qs[(d4+3)*68+q]=bf2f(v.w);
    }
  }
  float cacc[4][4] = {};
  float rs[4] = {};
  for (int m0 = 0; m0 < L_; m0 += 64) {
    {
      const int r = tid >> 4, d4 = (tid & 15) << 2;
#pragma unroll
      for (int p = 0; p < 4; ++p) {
        const int m = (p<<4) + r;
        ushort4 v = *(const ushort4*)(Kp + (size_t)(m0+m) * DH_ + d4);
        float f0=bf2f(v.x), f1=bf2f(v.y), f2=bf2f(v.z), f3=bf2f(v.w);
        B1[(d4+0)*68+m]=f0; B1[(d4+1)*68+m]=f1; B1[(d4+2)*68+m]=f2; B1[(d4+3)*68+m]=f3;
        *(float4*)&Ksm[m*68 + d4] = make_float4(f0, f1, f2, f3);
      }
      if (tid < 64) sal_s[tid] = sal[(size_t)bh * L_ + m0 + tid];
    }
    __syncthreads();
    float s[4][4] = {};
#pragma unroll 8
    for (int d = 0; d < 64; ++d) {
      float4 av = *(const float4*)&Qs[d*68 + (ty<<2)];
      float4 kv = *(const float4*)&B1[d*68 + (tx<<2)];
      float a[4] = {av.x, av.y, av.z, av.w};
      float k[4] = {kv.x, kv.y, kv.z, kv.w};
#pragma unroll
      for (int i = 0; i < 4; ++i)
#pragma unroll
        for (int j = 0; j < 4; ++j)
          s[i][j] = fmaf(a[i], k[j], s[i][j]);
    }
    float p[4][4];
#pragma unroll
    for (int i = 0; i < 4; ++i)
#pragma unroll
      for (int j = 0; j < 4; ++j)
        p[i][j] = __expf(fmaf(s[i][j], 0.125f, sal_s[(tx<<2)+j]));
    __syncthreads();  // all done reading B1 as K[d][m]
#pragma unroll
    for (int i = 0; i < 4; ++i) {
      const int q = (ty<<2) + i;
      *(float4*)(attn + ((size_t)bh * L_ + q0 + q) * L_ + m0 + (tx<<2)) =
          make_float4(p[i][0], p[i][1], p[i][2], p[i][3]);
      rs[i] += p[i][0] + p[i][1] + p[i][2] + p[i][3];
#pragma unroll
      for (int j = 0; j < 4; ++j) B1[q*69 + (tx<<2) + j] = p[i][j];
    }
    __syncthreads();  // Ps visible
#pragma unroll 8
    for (int m = 0; m < 64; ++m) {
      float4 kv = *(const float4*)&Ksm[m*68 + (tx<<2)];
      float pv[4];
#pragma unroll
      for (int i = 0; i < 4; ++i) pv[i] = B1[((ty<<2)+i)*69 + m];
#pragma unroll
      for (int i = 0; i < 4; ++i) {
        cacc[i][0] = fmaf(pv[i], kv.x, cacc[i][0]);
        cacc[i][1] = fmaf(pv[i], kv.y, cacc[i][1]);
        cacc[i][2] = fmaf(pv[i], kv.z, cacc[i][2]);
        cacc[i][3] = fmaf(pv[i], kv.w, cacc[i][3]);
      }
    }
    __syncthreads();  // before next tile overwrites B1/Ksm/sal_s
  }
  // reduce rowsums across tx (16 partials per q row)
#pragma unroll
  for (int i = 0; i < 4; ++i) B1[((ty<<2)+i)*17 + tx] = rs[i];
  __syncthreads();
  if (tid < 64) {
    float ssum = 0.f;
#pragma unroll
    for (int t = 0; t < 16; ++t) ssum += B1[tid*17 + t];
    const float inv = 1.0f / ssum;
    inv_s[tid] = inv;
    invS[(size_t)bh * L_ + q0 + tid] = inv;
  }
  __syncthreads();
  const int b = bh >> 3, h = bh & 7;
#pragma unroll
  for (int i = 0; i < 4; ++i) {
    const int q = (ty<<2) + i;
    const float inv = inv_s[q];
    *(float4*)(ctx + ((size_t)(b*L_ + q0 + q)) * DC_ + h*DH_ + (tx<<2)) =
        make_float4(cacc[i][0]*inv, cacc[i][1]*inv, cacc[i][2]*inv, cacc[i][3]*inv);
  }
}

// ---------------------------------------------------------------------------
// In-place rescale of attn rows by invS. 4 fp32 (16B) per thread.
// ---------------------------------------------------------------------------
__global__ __launch_bounds__(256) void norm_k(float* __restrict__ attn,
                                              const float* __restrict__ invS)
{
  const size_t idx = (size_t)blockIdx.x * 256 + threadIdx.x;
  const size_t e = idx << 2;
  const float inv = invS[e >> 11];
  float4 v = *(float4*)(attn + e);
  v.x *= inv; v.y *= inv; v.z *= inv; v.w *= inv;
  *(float4*)(attn + e) = v;
}

// ---------------------------------------------------------------------------
// gate = sigmoid(garg); y2 = gate*tanh(x2)+(1-gate)*x2
// ---------------------------------------------------------------------------
__global__ __launch_bounds__(256) void gate_k(const float* __restrict__ garg,
                                              const float* __restrict__ src,
                                              float* __restrict__ y2)
{
  const int idx = blockIdx.x * 256 + threadIdx.x;   // over 4096*128
  const int m = idx >> 7;
  const int c = (idx & 127) << 2;
  float4 g4 = *(const float4*)(garg + (size_t)m * DC_ + c);
  float4 x2 = *(const float4*)(src + (size_t)m * DM_ + DC_ + c);
  float g[4] = {g4.x, g4.y, g4.z, g4.w};
  float x[4] = {x2.x, x2.y, x2.z, x2.w};
  float y[4];
#pragma unroll
  for (int t = 0; t < 4; ++t) {
    const float s = 1.f / (1.f + __expf(-g[t]));
    y[t] = s * tanhf(x[t]) + (1.f - s) * x[t];
  }
  *(float4*)(y2 + (size_t)m * DC_ + c) = make_float4(y[0], y[1], y[2], y[3]);
}

// ---------------------------------------------------------------------------
extern "C" void kernel_launch(void* const* d_in, const int* in_sizes, int n_in,
                              void* d_out, int out_size, void* d_ws, size_t ws_size,
                              hipStream_t stream)
{
  const float* src   = (const float*)d_in[0];
  const float* Wq    = (const float*)d_in[1];
  const float* bq    = (const float*)d_in[2];
  const float* Wk    = (const float*)d_in[3];
  const float* bk    = (const float*)d_in[4];
  const float* convw = (const float*)d_in[5];
  const float* convb = (const float*)d_in[6];
  const float* Wst   = (const float*)d_in[7];
  const float* bst   = (const float*)d_in[8];
  const float* Wout  = (const float*)d_in[9];
  const float* bout  = (const float*)d_in[10];

  float* out  = (float*)d_out;                 // fp32: reference output dtype
  float* attn = out + (size_t)MR_ * DM_;       // output first (4,194,304), then attn (67,108,864)

  // Workspace (16.25 MiB total, overlaid):
  //   [Qh bf16 4MiB][Kh bf16 4MiB][salb 128KiB][invS 128KiB][ctx fp32 8MiB]
  //   garg (fp32 8MiB) overlays Qh+Kh after attn_k is done.
  //   y2   (fp32 8MiB) overlays ctx after the st-GEMM is done.
  u16*   Qh   = (u16*)d_ws;                           // [16][2048][64] bf16
  u16*   Kh   = Qh + (size_t)BH_ * L_ * DH_;          // [16][2048][64] bf16
  float* salb = (float*)(Kh + (size_t)BH_ * L_ * DH_);// [16][2048]
  float* invS = salb + (size_t)BH_ * L_;              // [16][2048]
  float* ctx  = invS + (size_t)BH_ * L_;              // [4096][512]
  float* garg = (float*)Qh;                           // overlays Qh+Kh (8MiB)
  float* y2b  = ctx;                                  // overlays ctx (8MiB)

  (void)in_sizes; (void)n_in; (void)out_size; (void)ws_size;

  // Q = x1 @ Wq^T + bq -> bf16 heads layout; K likewise
  gemm_k<3><<<dim3(DC_/64, MR_/64), 256, 0, stream>>>(src, DM_, nullptr, Wq, DC_, bq, nullptr, Qh, DC_, DC_);
  gemm_k<3><<<dim3(DC_/64, MR_/64), 256, 0, stream>>>(src, DM_, nullptr, Wk, DC_, bk, nullptr, Kh, DC_, DC_);
  // saliency conv
  conv_k<<<dim3(L_/32, B_), 256, 0, stream>>>(src, convw, convb, salb);
  // attention: unnormalized p -> attn (fp32), invS, normalized ctx
  attn_k<<<dim3(L_/64, BH_), 256, 0, stream>>>(Qh, Kh, salb, attn, invS, ctx);
  // rescale attn in place (67,108,864 floats / 4 per thread / 256 per block)
  norm_k<<<dim3(65536), 256, 0, stream>>>(attn, invS);
  // gate arg = ctx @ Wst^T + bst  (garg overlays Qh/Kh, now free)
  gemm_k<0><<<dim3(DC_/64, MR_/64), 256, 0, stream>>>(ctx, DC_, nullptr, Wst, DC_, bst, garg, nullptr, DC_, DC_);
  // y2 gating (y2 overlays ctx, now free)
  gate_k<<<dim3((MR_*DC_/4)/256), 256, 0, stream>>>(garg, src, y2b);
  // output = [x1 | y2] @ Wout^T + bout (fp32 store); x1 read from src, y2 from y2b
  gemm_k<2><<<dim3(DM_/64, MR_/64), 256, 0, stream>>>(src, DM_, y2b, Wout, DM_, bout, out, nullptr, DM_, DM_);
}

// Round 5
// 421.050 us; speedup vs baseline: 1.5049x; 1.5049x over previous
//
#include <hip/hip_runtime.h>
#include <hip/hip_bf16.h>
#include <math.h>

#define B_ 2
#define L_ 2048
#define DM_ 1024
#define DC_ 512
#define NH_ 8
#define DH_ 64
#define MR_ (B_*L_)   // 4096 rows
#define BH_ (B_*NH_)  // 16

typedef unsigned short u16;
typedef unsigned int u32;
typedef __attribute__((ext_vector_type(8))) short bf16x8;
typedef __attribute__((ext_vector_type(4))) float f32x4;

static __device__ __forceinline__ u16 f2bf(float x) {
  union { float f; u32 u; } v; v.f = x;
  u32 r = (v.u + 0x7fffu + ((v.u >> 16) & 1u)) >> 16;  // RNE
  return (u16)r;
}
static __device__ __forceinline__ float bf2f(u16 x) {
  union { u32 u; float f; } v; v.u = ((u32)x) << 16;
  return v.f;
}

// ---------------------------------------------------------------------------
// Generic C = A @ W^T + bias GEMM. 64x64 tile, BK=16, 256 thr, 4x4/thread.
// MODE 0: Cf[m*Ndim+n] fp32
// MODE 2: Cf[m*Ndim+n] fp32, A split at k=512: k<512 from A (lda), else A2 (ld 512)
// MODE 3: bf16 heads layout Cb[((b*8+h)*L+l)*64+d]
// ---------------------------------------------------------------------------
template<int MODE>
__global__ __launch_bounds__(256) void gemm_k(
    const float* __restrict__ A, int lda,
    const float* __restrict__ A2,
    const float* __restrict__ W, int ldw,
    const float* __restrict__ bias,
    float* __restrict__ Cf, u16* __restrict__ Cb,
    int Ndim, int Kdim)
{
  __shared__ float As[16][68];
  __shared__ float Ws[16][68];
  const int tid = threadIdx.x;
  const int tx = tid & 15, ty = tid >> 4;
  const int m0 = blockIdx.y << 6, n0 = blockIdx.x << 6;
  const int lr = tid >> 2;          // 0..63
  const int lk = (tid & 3) << 2;    // 0,4,8,12
  float acc[4][4] = {};
  const float* Wp = W + (size_t)(n0 + lr) * ldw + lk;
  for (int k0 = 0; k0 < Kdim; k0 += 16) {
    const float* ap;
    if (MODE == 2 && k0 >= 512)
      ap = A2 + (size_t)(m0 + lr) * 512 + (k0 - 512) + lk;
    else
      ap = A + (size_t)(m0 + lr) * lda + k0 + lk;
    float4 a4 = *(const float4*)ap;
    float4 w4 = *(const float4*)(Wp + k0);
    As[lk+0][lr]=a4.x; As[lk+1][lr]=a4.y; As[lk+2][lr]=a4.z; As[lk+3][lr]=a4.w;
    Ws[lk+0][lr]=w4.x; Ws[lk+1][lr]=w4.y; Ws[lk+2][lr]=w4.z; Ws[lk+3][lr]=w4.w;
    __syncthreads();
#pragma unroll
    for (int kk = 0; kk < 16; ++kk) {
      float4 av = *(const float4*)&As[kk][ty<<2];
      float4 wv = *(const float4*)&Ws[kk][tx<<2];
      float a[4] = {av.x, av.y, av.z, av.w};
      float w[4] = {wv.x, wv.y, wv.z, wv.w};
#pragma unroll
      for (int i = 0; i < 4; ++i)
#pragma unroll
        for (int j = 0; j < 4; ++j)
          acc[i][j] = fmaf(a[i], w[j], acc[i][j]);
    }
    __syncthreads();
  }
#pragma unroll
  for (int i = 0; i < 4; ++i) {
    const int m = m0 + (ty<<2) + i;
    const int n = n0 + (tx<<2);
    float v0 = acc[i][0] + bias[n+0];
    float v1 = acc[i][1] + bias[n+1];
    float v2 = acc[i][2] + bias[n+2];
    float v3 = acc[i][3] + bias[n+3];
    if (MODE == 0 || MODE == 2) {
      *(float4*)(Cf + (size_t)m * Ndim + n) = make_float4(v0, v1, v2, v3);
    } else {
      const int b = m >> 11, l = m & (L_-1), h = n >> 6, d = n & (DH_-1);
      ushort4 o; o.x = f2bf(v0); o.y = f2bf(v1); o.z = f2bf(v2); o.w = f2bf(v3);
      *(ushort4*)(Cb + ((size_t)(b*NH_ + h) * L_ + l) * DH_ + d) = o;
    }
  }
}

// ---------------------------------------------------------------------------
// Saliency conv1d: sal[b][h][l] = sum_c sum_t x1[b][l+t-1][c]*cw[h][c][t] + cb[h]
// ---------------------------------------------------------------------------
__global__ __launch_bounds__(256) void conv_k(
    const float* __restrict__ src, const float* __restrict__ cw,
    const float* __restrict__ cb, float* __restrict__ sal)
{
  __shared__ float xs[34][260];
  const int b = blockIdx.y;
  const int l0 = blockIdx.x << 5;
  const int tid = threadIdx.x;
  const int li = tid >> 3, h = tid & 7;
  float acc = cb[h];
  for (int c0 = 0; c0 < DC_; c0 += 256) {
    __syncthreads();
    for (int t = tid; t < 34*64; t += 256) {
      const int r = t >> 6;
      const int c4 = (t & 63) << 2;
      const int l = l0 - 1 + r;
      float4 v = make_float4(0.f, 0.f, 0.f, 0.f);
      if (l >= 0 && l < L_)
        v = *(const float4*)(src + (size_t)(b*L_ + l) * DM_ + c0 + c4);
      *(float4*)&xs[r][c4] = v;
    }
    __syncthreads();
    for (int c = 0; c < 256; ++c) {
      const float* w = cw + ((size_t)h * DC_ + c0 + c) * 3;
      acc += xs[li+0][c]*w[0] + xs[li+1][c]*w[1] + xs[li+2][c]*w[2];
    }
  }
  sal[(size_t)(b*NH_ + h) * L_ + l0 + li] = acc;
}

// ---------------------------------------------------------------------------
// MFMA attention. Block = (bh, 64-q tile), 256 thr = 4 waves, wave w owns
// q-strip [w*16, w*16+16). Two sweeps over K tiles of 64:
//  sweep1: QK^T (mfma 16x16x32 bf16) + exp -> rowsums -> invS (in-lane).
//  sweep2: recompute p, scale by invS, write attn (fp32, coalesced via LDS
//          transpose), p->bf16 Ps, PV mfma with Kt (LDS-built transpose).
// Fragment maps (m89/m91): A/B: lane&15 = M/N, (lane>>4)*8+j = K.
//                          D: col = lane&15, row = (lane>>4)*4 + reg.
// All bf16 LDS tiles stride 72 (144B rows -> conflict-free b128 patterns).
// ---------------------------------------------------------------------------
__global__ __launch_bounds__(256) void attn_k(
    const u16* __restrict__ Qh, const u16* __restrict__ Kh,
    const float* __restrict__ sal, float* __restrict__ attn,
    float* __restrict__ ctx)
{
  __shared__ u16 Qs[64*72];
  __shared__ u16 Kn[64*72];
  __shared__ u16 Kt[64*72];
  __shared__ u16 Ps[4*16*72];
  __shared__ float sal_s[64];

  const int tid = threadIdx.x;
  const int wid = tid >> 6;
  const int lane = tid & 63;
  const int lr = lane & 15;
  const int lg = lane >> 4;
  const int bh = blockIdx.y;
  const int q0 = blockIdx.x << 6;
  const u16* Kbase = Kh + (size_t)bh * L_ * DH_;

  // stage Q tile (64x64 bf16), coalesced
#pragma unroll
  for (int p = 0; p < 2; ++p) {
    const int r = (tid >> 3) + (p << 5);
    const int s = tid & 7;
    *(bf16x8*)&Qs[r*72 + s*8] =
        *(const bf16x8*)(Qh + ((size_t)bh * L_ + q0 + r) * DH_ + s*8);
  }
  __syncthreads();
  bf16x8 qf[2];
  qf[0] = *(bf16x8*)&Qs[(wid*16 + lr)*72 + lg*8];
  qf[1] = *(bf16x8*)&Qs[(wid*16 + lr)*72 + 32 + lg*8];

  // ---------------- sweep 1: rowsums ----------------
  float rs[4] = {0.f, 0.f, 0.f, 0.f};
  for (int m0 = 0; m0 < L_; m0 += 64) {
#pragma unroll
    for (int p = 0; p < 2; ++p) {
      const int r = (tid >> 3) + (p << 5);
      const int s = tid & 7;
      *(bf16x8*)&Kn[r*72 + s*8] =
          *(const bf16x8*)(Kbase + (size_t)(m0 + r) * DH_ + s*8);
    }
    if (tid < 64) sal_s[tid] = sal[(size_t)bh * L_ + m0 + tid];
    __syncthreads();
#pragma unroll
    for (int ms = 0; ms < 4; ++ms) {
      f32x4 acc = {0.f, 0.f, 0.f, 0.f};
#pragma unroll
      for (int ks = 0; ks < 2; ++ks) {
        bf16x8 kf = *(bf16x8*)&Kn[(ms*16 + lr)*72 + ks*32 + lg*8];
        acc = __builtin_amdgcn_mfma_f32_16x16x32_bf16(qf[ks], kf, acc, 0, 0, 0);
      }
      const float sl = sal_s[ms*16 + lr];
#pragma unroll
      for (int r = 0; r < 4; ++r)
        rs[r] += __expf(fmaf(acc[r], 0.125f, sl));
    }
    __syncthreads();
  }
  // reduce over the 16 column-lanes; invS lands in exactly the lanes sweep2 needs
#pragma unroll
  for (int r = 0; r < 4; ++r) {
    float v = rs[r];
    v += __shfl_xor(v, 1); v += __shfl_xor(v, 2);
    v += __shfl_xor(v, 4); v += __shfl_xor(v, 8);
    rs[r] = 1.0f / v;
  }

  // ---------------- sweep 2: attn store + PV ----------------
  f32x4 pvacc[4] = {{0.f,0.f,0.f,0.f},{0.f,0.f,0.f,0.f},
                    {0.f,0.f,0.f,0.f},{0.f,0.f,0.f,0.f}};
  for (int m0 = 0; m0 < L_; m0 += 64) {
#pragma unroll
    for (int p = 0; p < 2; ++p) {
      const int r = (tid >> 3) + (p << 5);
      const int s = tid & 7;
      *(bf16x8*)&Kn[r*72 + s*8] =
          *(const bf16x8*)(Kbase + (size_t)(m0 + r) * DH_ + s*8);
    }
    if (tid < 64) sal_s[tid] = sal[(size_t)bh * L_ + m0 + tid];
    __syncthreads();
    // build Kt[d][m] from Kn[m][d] through LDS (conflict-free-ish)
#pragma unroll
    for (int qd = 0; qd < 4; ++qd) {
      const int d = lane;
      const int mq = wid*4 + qd;          // 0..15
      ushort4 t;
      t.x = Kn[(mq*4+0)*72 + d]; t.y = Kn[(mq*4+1)*72 + d];
      t.z = Kn[(mq*4+2)*72 + d]; t.w = Kn[(mq*4+3)*72 + d];
      *(ushort4*)&Kt[d*72 + mq*4] = t;
    }
    __syncthreads();
    // QK^T + normalized p -> Ps (bf16)
#pragma unroll
    for (int ms = 0; ms < 4; ++ms) {
      f32x4 acc = {0.f, 0.f, 0.f, 0.f};
#pragma unroll
      for (int ks = 0; ks < 2; ++ks) {
        bf16x8 kf = *(bf16x8*)&Kn[(ms*16 + lr)*72 + ks*32 + lg*8];
        acc = __builtin_amdgcn_mfma_f32_16x16x32_bf16(qf[ks], kf, acc, 0, 0, 0);
      }
      const float sl = sal_s[ms*16 + lr];
#pragma unroll
      for (int r = 0; r < 4; ++r) {
        const float ph = __expf(fmaf(acc[r], 0.125f, sl)) * rs[r];
        Ps[(wid*16 + lg*4 + r)*72 + ms*16 + lr] = f2bf(ph);
      }
    }
    // attn store: re-read own strip from Ps, coalesced float4 stores
    {
      const int qr = lane >> 2;            // 0..15
      const int mseg = (lane & 3) << 4;    // 0,16,32,48
      bf16x8 v0 = *(bf16x8*)&Ps[(wid*16 + qr)*72 + mseg];
      bf16x8 v1 = *(bf16x8*)&Ps[(wid*16 + qr)*72 + mseg + 8];
      float* dst = attn + ((size_t)bh * L_ + q0 + wid*16 + qr) * L_ + m0 + mseg;
#pragma unroll
      for (int t = 0; t < 2; ++t) {
        bf16x8 v = t ? v1 : v0;
        float4 f0 = make_float4(bf2f((u16)v[0]), bf2f((u16)v[1]),
                                bf2f((u16)v[2]), bf2f((u16)v[3]));
        float4 f1 = make_float4(bf2f((u16)v[4]), bf2f((u16)v[5]),
                                bf2f((u16)v[6]), bf2f((u16)v[7]));
        *(float4*)(dst + t*8)     = f0;
        *(float4*)(dst + t*8 + 4) = f1;
      }
    }
    // PV: ctx += P @ K  (A = Ps, B = Kt)
#pragma unroll
    for (int ks = 0; ks < 2; ++ks) {
      bf16x8 pa = *(bf16x8*)&Ps[(wid*16 + lr)*72 + ks*32 + lg*8];
#pragma unroll
      for (int ds = 0; ds < 4; ++ds) {
        bf16x8 kb = *(bf16x8*)&Kt[(ds*16 + lr)*72 + ks*32 + lg*8];
        pvacc[ds] = __builtin_amdgcn_mfma_f32_16x16x32_bf16(pa, kb, pvacc[ds], 0, 0, 0);
      }
    }
    __syncthreads();
  }
  // ctx store [b, l, h*64+d]
  const int b = bh >> 3, h = bh & 7;
#pragma unroll
  for (int ds = 0; ds < 4; ++ds)
#pragma unroll
    for (int r = 0; r < 4; ++r)
      ctx[((size_t)(b*L_ + q0 + wid*16 + lg*4 + r)) * DC_ + h*DH_ + ds*16 + lr] =
          pvacc[ds][r];
}

// ---------------------------------------------------------------------------
// gate = sigmoid(garg); y2 = gate*tanh(x2)+(1-gate)*x2
// ---------------------------------------------------------------------------
__global__ __launch_bounds__(256) void gate_k(const float* __restrict__ garg,
                                              const float* __restrict__ src,
                                              float* __restrict__ y2)
{
  const int idx = blockIdx.x * 256 + threadIdx.x;   // over 4096*128
  const int m = idx >> 7;
  const int c = (idx & 127) << 2;
  float4 g4 = *(const float4*)(garg + (size_t)m * DC_ + c);
  float4 x2 = *(const float4*)(src + (size_t)m * DM_ + DC_ + c);
  float g[4] = {g4.x, g4.y, g4.z, g4.w};
  float x[4] = {x2.x, x2.y, x2.z, x2.w};
  float y[4];
#pragma unroll
  for (int t = 0; t < 4; ++t) {
    const float s = 1.f / (1.f + __expf(-g[t]));
    y[t] = s * tanhf(x[t]) + (1.f - s) * x[t];
  }
  *(float4*)(y2 + (size_t)m * DC_ + c) = make_float4(y[0], y[1], y[2], y[3]);
}

// ---------------------------------------------------------------------------
extern "C" void kernel_launch(void* const* d_in, const int* in_sizes, int n_in,
                              void* d_out, int out_size, void* d_ws, size_t ws_size,
                              hipStream_t stream)
{
  const float* src   = (const float*)d_in[0];
  const float* Wq    = (const float*)d_in[1];
  const float* bq    = (const float*)d_in[2];
  const float* Wk    = (const float*)d_in[3];
  const float* bk    = (const float*)d_in[4];
  const float* convw = (const float*)d_in[5];
  const float* convb = (const float*)d_in[6];
  const float* Wst   = (const float*)d_in[7];
  const float* bst   = (const float*)d_in[8];
  const float* Wout  = (const float*)d_in[9];
  const float* bout  = (const float*)d_in[10];

  float* out  = (float*)d_out;                 // fp32: reference output dtype
  float* attn = out + (size_t)MR_ * DM_;       // output (4,194,304), then attn (67,108,864)

  // Workspace (overlaid):
  //   [Qh bf16 4MiB][Kh bf16 4MiB][salb 128KiB][ctx fp32 8MiB]
  //   garg (fp32 8MiB) overlays Qh+Kh after attn_k; y2 overlays ctx after st-GEMM.
  u16*   Qh   = (u16*)d_ws;                           // [16][2048][64] bf16
  u16*   Kh   = Qh + (size_t)BH_ * L_ * DH_;          // [16][2048][64] bf16
  float* salb = (float*)(Kh + (size_t)BH_ * L_ * DH_);// [16][2048]
  float* ctx  = salb + (size_t)BH_ * L_;              // [4096][512]
  float* garg = (float*)Qh;                           // overlays Qh+Kh (8MiB)
  float* y2b  = ctx;                                  // overlays ctx (8MiB)

  (void)in_sizes; (void)n_in; (void)out_size; (void)ws_size;

  // Q = x1 @ Wq^T + bq -> bf16 heads layout; K likewise
  gemm_k<3><<<dim3(DC_/64, MR_/64), 256, 0, stream>>>(src, DM_, nullptr, Wq, DC_, bq, nullptr, Qh, DC_, DC_);
  gemm_k<3><<<dim3(DC_/64, MR_/64), 256, 0, stream>>>(src, DM_, nullptr, Wk, DC_, bk, nullptr, Kh, DC_, DC_);
  // saliency conv
  conv_k<<<dim3(L_/32, B_), 256, 0, stream>>>(src, convw, convb, salb);
  // MFMA attention: normalized attn (fp32) + ctx, no separate norm pass
  attn_k<<<dim3(L_/64, BH_), 256, 0, stream>>>(Qh, Kh, salb, attn, ctx);
  // gate arg = ctx @ Wst^T + bst  (garg overlays Qh/Kh, now free)
  gemm_k<0><<<dim3(DC_/64, MR_/64), 256, 0, stream>>>(ctx, DC_, nullptr, Wst, DC_, bst, garg, nullptr, DC_, DC_);
  // y2 gating (y2 overlays ctx, now free)
  gate_k<<<dim3((MR_*DC_/4)/256), 256, 0, stream>>>(garg, src, y2b);
  // output = [x1 | y2] @ Wout^T + bout (fp32 store); x1 from src, y2 from y2b
  gemm_k<2><<<dim3(DM_/64, MR_/64), 256, 0, stream>>>(src, DM_, y2b, Wout, DM_, bout, out, nullptr, DM_, DM_);
}

// Round 6
// 280.765 us; speedup vs baseline: 2.2569x; 1.4997x over previous
//
#include <hip/hip_runtime.h>
#include <hip/hip_bf16.h>
#include <math.h>

#define B_ 2
#define L_ 2048
#define DM_ 1024
#define DC_ 512
#define NH_ 8
#define DH_ 64
#define MR_ (B_*L_)   // 4096 rows
#define BH_ (B_*NH_)  // 16

typedef unsigned short u16;
typedef unsigned int u32;
typedef __attribute__((ext_vector_type(8))) short bf16x8;
typedef __attribute__((ext_vector_type(4))) float f32x4;

static __device__ __forceinline__ u16 f2bf(float x) {
  union { float f; u32 u; } v; v.f = x;
  u32 r = (v.u + 0x7fffu + ((v.u >> 16) & 1u)) >> 16;  // RNE
  return (u16)r;
}
static __device__ __forceinline__ float bf2f(u16 x) {
  union { u32 u; float f; } v; v.u = ((u32)x) << 16;
  return v.f;
}

// ---------------------------------------------------------------------------
// One-shot fp32 -> bf16 conversion: x1 (from src, stride 1024), Wq, Wk, Wst,
// Wout. Grid = 3840 x 256, 4 elems (one float4) per thread.
// vec counts: x1 524288 | Wq 65536 | Wk 65536 | Wst 65536 | Wout 262144
// ---------------------------------------------------------------------------
__global__ __launch_bounds__(256) void cvt_k(
    const float* __restrict__ src,
    const float* __restrict__ Wq, const float* __restrict__ Wk,
    const float* __restrict__ Wst, const float* __restrict__ Wout,
    u16* __restrict__ x1b, u16* __restrict__ Wqb, u16* __restrict__ Wkb,
    u16* __restrict__ Wstb, u16* __restrict__ Woutb)
{
  int v = blockIdx.x * 256 + threadIdx.x;
  if (v < 524288) {
    const int m = v >> 7, c = (v & 127) << 2;
    float4 f = *(const float4*)(src + (size_t)m * DM_ + c);
    *(ushort4*)(x1b + (size_t)m * DC_ + c) =
        make_ushort4(f2bf(f.x), f2bf(f.y), f2bf(f.z), f2bf(f.w));
    return;
  }
  v -= 524288;
  const float* sp; u16* dp;
  if (v < 65536)       { sp = Wq;   dp = Wqb; }
  else if (v < 131072) { sp = Wk;   dp = Wkb;   v -= 65536; }
  else if (v < 196608) { sp = Wst;  dp = Wstb;  v -= 131072; }
  else                 { sp = Wout; dp = Woutb; v -= 196608; }
  float4 f = *(const float4*)(sp + (size_t)v * 4);
  *(ushort4*)(dp + (size_t)v * 4) =
      make_ushort4(f2bf(f.x), f2bf(f.y), f2bf(f.z), f2bf(f.w));
}

// ---------------------------------------------------------------------------
// bf16 MFMA GEMM: C = A @ W^T + bias. Block tile 128 x BN, BK=32, 256 thr =
// 4 waves. BN=128: 2x2 waves of 64x64 (4 M-frags). BN=64: 4x1 waves of 32x64
// (2 M-frags). LDS tiles stride 40 bf16 (80 B rows, 16B-aligned, 2-way bank
// aliasing = free).
// MODE 0: Ob = bf16 heads layout [((b*8+h)*L+l)*64+d]
// MODE 1: fused gate: v=garg; y2 = sig(v)*tanh(x2)+(1-sig(v))*x2 -> Ob bf16 [m][n]
// MODE 2: A split at k=512 (A | A2, both stride 512); Of fp32 [m][n]
// Fragment map (m89/m91): A/B: lane&15 = M/N, (lane>>4)*8+j = K.
//                         D: col = lane&15, row = (lane>>4)*4 + reg.
// ---------------------------------------------------------------------------
template<int MODE, int BN>
__global__ __launch_bounds__(256) void mgemm_k(
    const u16* __restrict__ A, const u16* __restrict__ A2,
    const u16* __restrict__ W, const float* __restrict__ bias,
    const float* __restrict__ src, u16* __restrict__ Ob,
    float* __restrict__ Of, int Ndim, int Kdim)
{
  constexpr int MF = (BN == 128) ? 4 : 2;   // M-frags per wave
  constexpr int WC = BN / 64;               // wave columns
  __shared__ u16 As[128 * 40];
  __shared__ u16 Ws[BN * 40];
  const int tid = threadIdx.x;
  const int wid = tid >> 6, lane = tid & 63;
  const int lr = lane & 15, lg = lane >> 4;
  const int wr = wid / WC, wc = wid % WC;
  const int m0 = blockIdx.y << 7;
  const int n0 = blockIdx.x * BN;

  f32x4 acc[MF][4];
#pragma unroll
  for (int mi = 0; mi < MF; ++mi)
#pragma unroll
    for (int ni = 0; ni < 4; ++ni)
      acc[mi][ni] = (f32x4){0.f, 0.f, 0.f, 0.f};

  for (int k0 = 0; k0 < Kdim; k0 += 32) {
    // stage A: 128 x 32 (16 elems per thread)
    {
      const int row = tid >> 1, seg = (tid & 1) << 4;
      const u16* ap;
      if (MODE == 2)
        ap = (k0 < 512) ? A  + (size_t)(m0 + row) * 512 + k0 + seg
                        : A2 + (size_t)(m0 + row) * 512 + (k0 - 512) + seg;
      else
        ap = A + (size_t)(m0 + row) * Kdim + k0 + seg;
      *(bf16x8*)&As[row * 40 + seg]     = *(const bf16x8*)ap;
      *(bf16x8*)&As[row * 40 + seg + 8] = *(const bf16x8*)(ap + 8);
    }
    // stage W: BN x 32
    if (BN == 128) {
      const int row = tid >> 1, seg = (tid & 1) << 4;
      const u16* wp = W + (size_t)(n0 + row) * Kdim + k0 + seg;
      *(bf16x8*)&Ws[row * 40 + seg]     = *(const bf16x8*)wp;
      *(bf16x8*)&Ws[row * 40 + seg + 8] = *(const bf16x8*)(wp + 8);
    } else {
      const int row = tid >> 2, seg = (tid & 3) << 3;
      *(bf16x8*)&Ws[row * 40 + seg] =
          *(const bf16x8*)(W + (size_t)(n0 + row) * Kdim + k0 + seg);
    }
    __syncthreads();
    bf16x8 af[MF], bfr[4];
#pragma unroll
    for (int mi = 0; mi < MF; ++mi)
      af[mi] = *(bf16x8*)&As[(wr * (MF * 16) + mi * 16 + lr) * 40 + lg * 8];
#pragma unroll
    for (int ni = 0; ni < 4; ++ni)
      bfr[ni] = *(bf16x8*)&Ws[(wc * 64 + ni * 16 + lr) * 40 + lg * 8];
#pragma unroll
    for (int mi = 0; mi < MF; ++mi)
#pragma unroll
      for (int ni = 0; ni < 4; ++ni)
        acc[mi][ni] = __builtin_amdgcn_mfma_f32_16x16x32_bf16(
            af[mi], bfr[ni], acc[mi][ni], 0, 0, 0);
    __syncthreads();
  }

  // epilogue
#pragma unroll
  for (int mi = 0; mi < MF; ++mi)
#pragma unroll
    for (int ni = 0; ni < 4; ++ni)
#pragma unroll
      for (int r = 0; r < 4; ++r) {
        const int m = m0 + wr * (MF * 16) + mi * 16 + lg * 4 + r;
        const int n = n0 + wc * 64 + ni * 16 + lr;
        const float v = acc[mi][ni][r] + bias[n];
        if (MODE == 0) {
          const int b = m >> 11, l = m & (L_ - 1), h = n >> 6, d = n & (DH_ - 1);
          Ob[((size_t)(b * NH_ + h) * L_ + l) * DH_ + d] = f2bf(v);
        } else if (MODE == 1) {
          const float x2 = src[(size_t)m * DM_ + DC_ + n];
          const float s = 1.f / (1.f + __expf(-v));
          Ob[(size_t)m * DC_ + n] = f2bf(s * tanhf(x2) + (1.f - s) * x2);
        } else {
          Of[(size_t)m * Ndim + n] = v;
        }
      }
}

// ---------------------------------------------------------------------------
// Saliency conv1d: sal[b][h][l] = sum_c sum_t x1[b][l+t-1][c]*cw[h][c][t] + cb[h]
// ---------------------------------------------------------------------------
__global__ __launch_bounds__(256) void conv_k(
    const float* __restrict__ src, const float* __restrict__ cw,
    const float* __restrict__ cb, float* __restrict__ sal)
{
  __shared__ float xs[34][260];
  const int b = blockIdx.y;
  const int l0 = blockIdx.x << 5;
  const int tid = threadIdx.x;
  const int li = tid >> 3, h = tid & 7;
  float acc = cb[h];
  for (int c0 = 0; c0 < DC_; c0 += 256) {
    __syncthreads();
    for (int t = tid; t < 34*64; t += 256) {
      const int r = t >> 6;
      const int c4 = (t & 63) << 2;
      const int l = l0 - 1 + r;
      float4 v = make_float4(0.f, 0.f, 0.f, 0.f);
      if (l >= 0 && l < L_)
        v = *(const float4*)(src + (size_t)(b*L_ + l) * DM_ + c0 + c4);
      *(float4*)&xs[r][c4] = v;
    }
    __syncthreads();
    for (int c = 0; c < 256; ++c) {
      const float* w = cw + ((size_t)h * DC_ + c0 + c) * 3;
      acc += xs[li+0][c]*w[0] + xs[li+1][c]*w[1] + xs[li+2][c]*w[2];
    }
  }
  sal[(size_t)(b*NH_ + h) * L_ + l0 + li] = acc;
}

// ---------------------------------------------------------------------------
// MFMA attention. Block = (bh, 64-q tile), 256 thr = 4 waves, wave w owns
// q-strip [w*16, w*16+16). Two sweeps over K tiles of 64:
//  sweep1: QK^T (mfma 16x16x32 bf16) + exp -> rowsums -> invS (in-lane).
//  sweep2: recompute p, scale by invS, write attn (fp32, coalesced via LDS
//          transpose), p->bf16 Ps, PV mfma with Kt (LDS-built transpose).
// ctx emitted as bf16 (feeds the bf16 MFMA st-GEMM).
// ---------------------------------------------------------------------------
__global__ __launch_bounds__(256) void attn_k(
    const u16* __restrict__ Qh, const u16* __restrict__ Kh,
    const float* __restrict__ sal, float* __restrict__ attn,
    u16* __restrict__ ctxb)
{
  __shared__ u16 Qs[64*72];
  __shared__ u16 Kn[64*72];
  __shared__ u16 Kt[64*72];
  __shared__ u16 Ps[4*16*72];
  __shared__ float sal_s[64];

  const int tid = threadIdx.x;
  const int wid = tid >> 6;
  const int lane = tid & 63;
  const int lr = lane & 15;
  const int lg = lane >> 4;
  const int bh = blockIdx.y;
  const int q0 = blockIdx.x << 6;
  const u16* Kbase = Kh + (size_t)bh * L_ * DH_;

  // stage Q tile (64x64 bf16), coalesced
#pragma unroll
  for (int p = 0; p < 2; ++p) {
    const int r = (tid >> 3) + (p << 5);
    const int s = tid & 7;
    *(bf16x8*)&Qs[r*72 + s*8] =
        *(const bf16x8*)(Qh + ((size_t)bh * L_ + q0 + r) * DH_ + s*8);
  }
  __syncthreads();
  bf16x8 qf[2];
  qf[0] = *(bf16x8*)&Qs[(wid*16 + lr)*72 + lg*8];
  qf[1] = *(bf16x8*)&Qs[(wid*16 + lr)*72 + 32 + lg*8];

  // ---------------- sweep 1: rowsums ----------------
  float rs[4] = {0.f, 0.f, 0.f, 0.f};
  for (int m0 = 0; m0 < L_; m0 += 64) {
#pragma unroll
    for (int p = 0; p < 2; ++p) {
      const int r = (tid >> 3) + (p << 5);
      const int s = tid & 7;
      *(bf16x8*)&Kn[r*72 + s*8] =
          *(const bf16x8*)(Kbase + (size_t)(m0 + r) * DH_ + s*8);
    }
    if (tid < 64) sal_s[tid] = sal[(size_t)bh * L_ + m0 + tid];
    __syncthreads();
#pragma unroll
    for (int ms = 0; ms < 4; ++ms) {
      f32x4 acc = {0.f, 0.f, 0.f, 0.f};
#pragma unroll
      for (int ks = 0; ks < 2; ++ks) {
        bf16x8 kf = *(bf16x8*)&Kn[(ms*16 + lr)*72 + ks*32 + lg*8];
        acc = __builtin_amdgcn_mfma_f32_16x16x32_bf16(qf[ks], kf, acc, 0, 0, 0);
      }
      const float sl = sal_s[ms*16 + lr];
#pragma unroll
      for (int r = 0; r < 4; ++r)
        rs[r] += __expf(fmaf(acc[r], 0.125f, sl));
    }
    __syncthreads();
  }
  // reduce over the 16 column-lanes; invS lands in the lanes sweep2 needs
#pragma unroll
  for (int r = 0; r < 4; ++r) {
    float v = rs[r];
    v += __shfl_xor(v, 1); v += __shfl_xor(v, 2);
    v += __shfl_xor(v, 4); v += __shfl_xor(v, 8);
    rs[r] = 1.0f / v;
  }

  // ---------------- sweep 2: attn store + PV ----------------
  f32x4 pvacc[4] = {{0.f,0.f,0.f,0.f},{0.f,0.f,0.f,0.f},
                    {0.f,0.f,0.f,0.f},{0.f,0.f,0.f,0.f}};
  for (int m0 = 0; m0 < L_; m0 += 64) {
#pragma unroll
    for (int p = 0; p < 2; ++p) {
      const int r = (tid >> 3) + (p << 5);
      const int s = tid & 7;
      *(bf16x8*)&Kn[r*72 + s*8] =
          *(const bf16x8*)(Kbase + (size_t)(m0 + r) * DH_ + s*8);
    }
    if (tid < 64) sal_s[tid] = sal[(size_t)bh * L_ + m0 + tid];
    __syncthreads();
    // build Kt[d][m] from Kn[m][d] through LDS
#pragma unroll
    for (int qd = 0; qd < 4; ++qd) {
      const int d = lane;
      const int mq = wid*4 + qd;          // 0..15
      ushort4 t;
      t.x = Kn[(mq*4+0)*72 + d]; t.y = Kn[(mq*4+1)*72 + d];
      t.z = Kn[(mq*4+2)*72 + d]; t.w = Kn[(mq*4+3)*72 + d];
      *(ushort4*)&Kt[d*72 + mq*4] = t;
    }
    __syncthreads();
    // QK^T + normalized p -> Ps (bf16)
#pragma unroll
    for (int ms = 0; ms < 4; ++ms) {
      f32x4 acc = {0.f, 0.f, 0.f, 0.f};
#pragma unroll
      for (int ks = 0; ks < 2; ++ks) {
        bf16x8 kf = *(bf16x8*)&Kn[(ms*16 + lr)*72 + ks*32 + lg*8];
        acc = __builtin_amdgcn_mfma_f32_16x16x32_bf16(qf[ks], kf, acc, 0, 0, 0);
      }
      const float sl = sal_s[ms*16 + lr];
#pragma unroll
      for (int r = 0; r < 4; ++r) {
        const float ph = __expf(fmaf(acc[r], 0.125f, sl)) * rs[r];
        Ps[(wid*16 + lg*4 + r)*72 + ms*16 + lr] = f2bf(ph);
      }
    }
    // attn store: re-read own strip from Ps, coalesced float4 stores
    {
      const int qr = lane >> 2;            // 0..15
      const int mseg = (lane & 3) << 4;    // 0,16,32,48
      bf16x8 v0 = *(bf16x8*)&Ps[(wid*16 + qr)*72 + mseg];
      bf16x8 v1 = *(bf16x8*)&Ps[(wid*16 + qr)*72 + mseg + 8];
      float* dst = attn + ((size_t)bh * L_ + q0 + wid*16 + qr) * L_ + m0 + mseg;
#pragma unroll
      for (int t = 0; t < 2; ++t) {
        bf16x8 v = t ? v1 : v0;
        float4 f0 = make_float4(bf2f((u16)v[0]), bf2f((u16)v[1]),
                                bf2f((u16)v[2]), bf2f((u16)v[3]));
        float4 f1 = make_float4(bf2f((u16)v[4]), bf2f((u16)v[5]),
                                bf2f((u16)v[6]), bf2f((u16)v[7]));
        *(float4*)(dst + t*8)     = f0;
        *(float4*)(dst + t*8 + 4) = f1;
      }
    }
    // PV: ctx += P @ K  (A = Ps, B = Kt)
#pragma unroll
    for (int ks = 0; ks < 2; ++ks) {
      bf16x8 pa = *(bf16x8*)&Ps[(wid*16 + lr)*72 + ks*32 + lg*8];
#pragma unroll
      for (int ds = 0; ds < 4; ++ds) {
        bf16x8 kb = *(bf16x8*)&Kt[(ds*16 + lr)*72 + ks*32 + lg*8];
        pvacc[ds] = __builtin_amdgcn_mfma_f32_16x16x32_bf16(pa, kb, pvacc[ds], 0, 0, 0);
      }
    }
    __syncthreads();
  }
  // ctx store [b, l, h*64+d] as bf16
  const int b = bh >> 3, h = bh & 7;
#pragma unroll
  for (int ds = 0; ds < 4; ++ds)
#pragma unroll
    for (int r = 0; r < 4; ++r)
      ctxb[((size_t)(b*L_ + q0 + wid*16 + lg*4 + r)) * DC_ + h*DH_ + ds*16 + lr] =
          f2bf(pvacc[ds][r]);
}

// ---------------------------------------------------------------------------
extern "C" void kernel_launch(void* const* d_in, const int* in_sizes, int n_in,
                              void* d_out, int out_size, void* d_ws, size_t ws_size,
                              hipStream_t stream)
{
  const float* src   = (const float*)d_in[0];
  const float* Wq    = (const float*)d_in[1];
  const float* bq    = (const float*)d_in[2];
  const float* Wk    = (const float*)d_in[3];
  const float* bk    = (const float*)d_in[4];
  const float* convw = (const float*)d_in[5];
  const float* convb = (const float*)d_in[6];
  const float* Wst   = (const float*)d_in[7];
  const float* bst   = (const float*)d_in[8];
  const float* Wout  = (const float*)d_in[9];
  const float* bout  = (const float*)d_in[10];

  float* out  = (float*)d_out;                 // fp32: reference output dtype
  float* attn = out + (size_t)MR_ * DM_;       // output (4,194,304), then attn (67,108,864)

  // Workspace, no overlays (~23.7 MiB):
  u16*   x1b   = (u16*)d_ws;                    // [4096][512]
  u16*   Qh    = x1b   + (size_t)MR_ * DC_;     // [16][2048][64]
  u16*   Kh    = Qh    + (size_t)BH_ * L_ * DH_;
  u16*   ctxb  = Kh    + (size_t)BH_ * L_ * DH_;// [4096][512]
  u16*   y2b   = ctxb  + (size_t)MR_ * DC_;     // [4096][512]
  u16*   Wqb   = y2b   + (size_t)MR_ * DC_;     // [512][512]
  u16*   Wkb   = Wqb   + (size_t)DC_ * DC_;
  u16*   Wstb  = Wkb   + (size_t)DC_ * DC_;
  u16*   Woutb = Wstb  + (size_t)DC_ * DC_;     // [1024][1024]
  float* salb  = (float*)(Woutb + (size_t)DM_ * DM_); // [16][2048]

  (void)in_sizes; (void)n_in; (void)out_size; (void)ws_size;

  // bf16 conversions
  cvt_k<<<dim3(3840), 256, 0, stream>>>(src, Wq, Wk, Wst, Wout,
                                        x1b, Wqb, Wkb, Wstb, Woutb);
  // Q = x1 @ Wq^T + bq -> bf16 heads layout; K likewise
  mgemm_k<0,64><<<dim3(8, 32), 256, 0, stream>>>(x1b, nullptr, Wqb, bq, nullptr, Qh, nullptr, DC_, DC_);
  mgemm_k<0,64><<<dim3(8, 32), 256, 0, stream>>>(x1b, nullptr, Wkb, bk, nullptr, Kh, nullptr, DC_, DC_);
  // saliency conv
  conv_k<<<dim3(L_/32, B_), 256, 0, stream>>>(src, convw, convb, salb);
  // MFMA attention: normalized attn (fp32) + ctx (bf16)
  attn_k<<<dim3(L_/64, BH_), 256, 0, stream>>>(Qh, Kh, salb, attn, ctxb);
  // garg = ctx @ Wst^T + bst, fused gate -> y2 (bf16)
  mgemm_k<1,64><<<dim3(8, 32), 256, 0, stream>>>(ctxb, nullptr, Wstb, bst, src, y2b, nullptr, DC_, DC_);
  // output = [x1 | y2] @ Wout^T + bout (fp32)
  mgemm_k<2,128><<<dim3(8, 32), 256, 0, stream>>>(x1b, y2b, Woutb, bout, nullptr, nullptr, out, DM_, DM_);
}